// Round 1
// baseline (953.234 us; speedup 1.0000x reference)
//
#include <hip/hip_runtime.h>
#include <hip/hip_bf16.h>

// SoftBERTScore loss, MI355X/gfx950.
// Pipeline: K0 init -> K1 E transpose+bf16 -> K2 exp(logits)@E (MFMA, split-K atomic)
//           -> K3 normalize+gather (bf16 out) -> K4 sim MFMA + masked max -> K5 F1/loss.
// ws usage: ~49.7 MB.

#define IGNORE_INDEX (-100)
#define NEG_INF (-1e9f)

typedef float f32x4 __attribute__((ext_vector_type(4)));
typedef __bf16 bf16x8 __attribute__((ext_vector_type(8)));

static constexpr int BB = 8, T = 512, V = 32128, DD = 512;
static constexpr int R = BB * T;              // 4096 rows
static constexpr int KITERS = V / 32;         // 1004
static constexpr int NCHUNK = 8;              // split-K
static constexpr int CHUNK = (KITERS + NCHUNK - 1) / NCHUNK;  // 126

__device__ __forceinline__ unsigned short f2bf(float f) {
  unsigned u = __float_as_uint(f);
  u += 0x7fffu + ((u >> 16) & 1u);   // RNE
  return (unsigned short)(u >> 16);
}
__device__ __forceinline__ unsigned pack2(float lo, float hi) {
  return (unsigned)f2bf(lo) | ((unsigned)f2bf(hi) << 16);
}
// order-preserving float<->uint for atomicMax
__device__ __forceinline__ unsigned fenc(float f) {
  unsigned u = __float_as_uint(f);
  return (u & 0x80000000u) ? ~u : (u | 0x80000000u);
}
__device__ __forceinline__ float fdec(unsigned e) {
  unsigned u = (e & 0x80000000u) ? (e & 0x7fffffffu) : ~e;
  return __uint_as_float(u);
}

// ---------------- K0: zero soft_pred accumulator, init max buffers ----------------
__global__ void k0_init(float* __restrict__ soft, unsigned* __restrict__ rowmax,
                        unsigned* __restrict__ colmax) {
  int idx = blockIdx.x * 256 + threadIdx.x;
  if (idx < R * DD) soft[idx] = 0.0f;
  if (idx < R) { rowmax[idx] = fenc(NEG_INF); colmax[idx] = fenc(NEG_INF); }
}

// ---------------- K1: E [V][D] fp32 -> eT [D][V] bf16 ----------------
__global__ void k1_transpose(const float* __restrict__ E, unsigned short* __restrict__ eT) {
  __shared__ unsigned short tile[64][72];   // pad to 72 to spread banks
  const int vb = blockIdx.x * 64, db = blockIdx.y * 64;
  const int t = threadIdx.x;
  {
    const int vl = t >> 2, dq = t & 3;
    const float4* src = (const float4*)(E + (size_t)(vb + vl) * DD + db + dq * 16);
    float4 x0 = src[0], x1 = src[1], x2 = src[2], x3 = src[3];
    unsigned short* dst = &tile[vl][dq * 16];
    dst[0]=f2bf(x0.x); dst[1]=f2bf(x0.y); dst[2]=f2bf(x0.z); dst[3]=f2bf(x0.w);
    dst[4]=f2bf(x1.x); dst[5]=f2bf(x1.y); dst[6]=f2bf(x1.z); dst[7]=f2bf(x1.w);
    dst[8]=f2bf(x2.x); dst[9]=f2bf(x2.y); dst[10]=f2bf(x2.z); dst[11]=f2bf(x2.w);
    dst[12]=f2bf(x3.x); dst[13]=f2bf(x3.y); dst[14]=f2bf(x3.z); dst[15]=f2bf(x3.w);
  }
  __syncthreads();
  {
    const int dl = t >> 2, vq = t & 3;
    unsigned v[16];
#pragma unroll
    for (int j = 0; j < 16; ++j) v[j] = tile[vq * 16 + j][dl];
    uint4 w0, w1;
    w0.x = v[0] | (v[1] << 16);  w0.y = v[2] | (v[3] << 16);
    w0.z = v[4] | (v[5] << 16);  w0.w = v[6] | (v[7] << 16);
    w1.x = v[8] | (v[9] << 16);  w1.y = v[10] | (v[11] << 16);
    w1.z = v[12] | (v[13] << 16); w1.w = v[14] | (v[15] << 16);
    uint4* out = (uint4*)(eT + (size_t)(db + dl) * V + vb + vq * 16);
    out[0] = w0; out[1] = w1;
  }
}

// ---------------- K2: soft_pred_unnorm = exp(logits) @ E  (bf16 MFMA) ----------------
// Tile: BM=128 rows x BN=512 (full D), BK=32, 512 threads (8 waves as 2x4, wave=64x128).
// Split-K over NCHUNK chunks, fp32 atomicAdd epilogue. LDS 100 KB dynamic (80B-padded rows).
__launch_bounds__(512, 2)
__global__ void k2_gemm(const float* __restrict__ logits,
                        const unsigned short* __restrict__ eT,
                        float* __restrict__ soft) {
  extern __shared__ unsigned short smem[];
  // A: [2][128][40] ushort @ 0 ; B: [2][512][40] ushort @ 10240
  const int t = threadIdx.x;
  const int lane = t & 63, wid = t >> 6;
  const int wm = wid >> 2, wn = wid & 3;
  const int rowbase = blockIdx.x * 128;
  const int it0 = blockIdx.y * CHUNK;
  const int itEnd = (it0 + CHUNK < KITERS) ? (it0 + CHUNK) : KITERS;

  const int am = t >> 2, akq = t & 3;  // A staging: row, k-octet (8 floats/thread)
  const int bn = t;                    // B staging: one 64B row slice per thread

  f32x4 acc[4][8];
#pragma unroll
  for (int i = 0; i < 4; ++i)
#pragma unroll
    for (int j = 0; j < 8; ++j) { f32x4 z = {0.f, 0.f, 0.f, 0.f}; acc[i][j] = z; }

  // prologue: stage it0 into buffer 0
  {
    const float4* ag = (const float4*)(logits + (size_t)(rowbase + am) * V + it0 * 32 + akq * 8);
    float4 a0 = ag[0], a1 = ag[1];
    const uint4* bg = (const uint4*)(eT + (size_t)bn * V + it0 * 32);
    uint4 b0 = bg[0], b1 = bg[1], b2 = bg[2], b3 = bg[3];
    uint4 w;
    w.x = pack2(__expf(a0.x), __expf(a0.y));
    w.y = pack2(__expf(a0.z), __expf(a0.w));
    w.z = pack2(__expf(a1.x), __expf(a1.y));
    w.w = pack2(__expf(a1.z), __expf(a1.w));
    *(uint4*)(smem + am * 40 + akq * 8) = w;
    unsigned short* Bd = smem + 10240 + bn * 40;
    *(uint4*)(Bd + 0) = b0; *(uint4*)(Bd + 8) = b1;
    *(uint4*)(Bd + 16) = b2; *(uint4*)(Bd + 24) = b3;
  }
  __syncthreads();

  int cur = 0;
  for (int it = it0; it < itEnd; ++it) {
    const bool hasNext = (it + 1) < itEnd;
    float4 a0, a1; uint4 b0, b1, b2, b3;
    if (hasNext) {
      const float4* ag = (const float4*)(logits + (size_t)(rowbase + am) * V + (it + 1) * 32 + akq * 8);
      a0 = ag[0]; a1 = ag[1];
      const uint4* bg = (const uint4*)(eT + (size_t)bn * V + (it + 1) * 32);
      b0 = bg[0]; b1 = bg[1]; b2 = bg[2]; b3 = bg[3];
    }
    const unsigned short* As = smem + cur * 5120;
    const unsigned short* Bs = smem + 10240 + cur * 20480;
    bf16x8 af[4], bf[8];
#pragma unroll
    for (int fm = 0; fm < 4; ++fm) {
      int row = wm * 64 + fm * 16 + (lane & 15);
      af[fm] = *(const bf16x8*)(As + row * 40 + (lane >> 4) * 8);
    }
#pragma unroll
    for (int fn = 0; fn < 8; ++fn) {
      int col = wn * 128 + fn * 16 + (lane & 15);
      bf[fn] = *(const bf16x8*)(Bs + col * 40 + (lane >> 4) * 8);
    }
#pragma unroll
    for (int fm = 0; fm < 4; ++fm)
#pragma unroll
      for (int fn = 0; fn < 8; ++fn)
        acc[fm][fn] = __builtin_amdgcn_mfma_f32_16x16x32_bf16(af[fm], bf[fn], acc[fm][fn], 0, 0, 0);
    if (hasNext) {
      const int nb = cur ^ 1;
      uint4 w;
      w.x = pack2(__expf(a0.x), __expf(a0.y));
      w.y = pack2(__expf(a0.z), __expf(a0.w));
      w.z = pack2(__expf(a1.x), __expf(a1.y));
      w.w = pack2(__expf(a1.z), __expf(a1.w));
      *(uint4*)(smem + nb * 5120 + am * 40 + akq * 8) = w;
      unsigned short* Bd = smem + 10240 + nb * 20480 + bn * 40;
      *(uint4*)(Bd + 0) = b0; *(uint4*)(Bd + 8) = b1;
      *(uint4*)(Bd + 16) = b2; *(uint4*)(Bd + 24) = b3;
    }
    __syncthreads();
    cur ^= 1;
  }

  // epilogue: atomic accumulate (split-K partial)
#pragma unroll
  for (int fm = 0; fm < 4; ++fm)
#pragma unroll
    for (int fn = 0; fn < 8; ++fn)
#pragma unroll
      for (int r4 = 0; r4 < 4; ++r4) {
        int row = rowbase + wm * 64 + fm * 16 + ((lane >> 4) << 2) + r4;
        int col = wn * 128 + fn * 16 + (lane & 15);
        atomicAdd(&soft[(size_t)row * DD + col], acc[fm][fn][r4]);
      }
}

// ---------------- K3: normalize soft_pred & gathered hard_ref -> bf16 ----------------
__global__ void k3_norm(const float* __restrict__ soft, const int* __restrict__ labels,
                        const float* __restrict__ E,
                        unsigned short* __restrict__ pnb, unsigned short* __restrict__ rnb) {
  const int r = blockIdx.x;
  const int t = threadIdx.x;            // 256
  const int lane = t & 63, wid = t >> 6;
  __shared__ float red[8];

  const float* row = soft + (size_t)r * DD;
  float v0 = row[t], v1 = row[t + 256];
  float ss = v0 * v0 + v1 * v1;
#pragma unroll
  for (int m = 1; m < 64; m <<= 1) ss += __shfl_xor(ss, m, 64);
  if (lane == 0) red[wid] = ss;
  __syncthreads();
  float s = red[0] + red[1] + red[2] + red[3];
  float sc = 1.0f / fmaxf(sqrtf(s), 1e-12f);
  pnb[(size_t)r * DD + t] = f2bf(v0 * sc);
  pnb[(size_t)r * DD + t + 256] = f2bf(v1 * sc);

  int lab = labels[r];
  int safe = (lab == IGNORE_INDEX) ? 0 : lab;
  const float* hrow = E + (size_t)safe * DD;
  float h0 = hrow[t], h1 = hrow[t + 256];
  float ss2 = h0 * h0 + h1 * h1;
#pragma unroll
  for (int m = 1; m < 64; m <<= 1) ss2 += __shfl_xor(ss2, m, 64);
  if (lane == 0) red[4 + wid] = ss2;
  __syncthreads();
  float s2 = red[4] + red[5] + red[6] + red[7];
  float sc2 = 1.0f / fmaxf(sqrtf(s2), 1e-12f);
  rnb[(size_t)r * DD + t] = f2bf(h0 * sc2);
  rnb[(size_t)r * DD + t + 256] = f2bf(h1 * sc2);
}

// ---------------- K4: sim = p_n @ r_n^T per batch; masked row/col maxes ----------------
// 1 wave per 64x64 sim tile; fragments loaded straight from global (L2/L3 resident).
__global__ void k4_sim(const unsigned short* __restrict__ pnb,
                       const unsigned short* __restrict__ rnb,
                       const int* __restrict__ labels,
                       unsigned* __restrict__ rowmax, unsigned* __restrict__ colmax) {
  const int lane = threadIdx.x;  // 64
  const int jt = blockIdx.x, it = blockIdx.y, b = blockIdx.z;
  const int i0 = it * 64, j0 = jt * 64;
  const unsigned short* pb = pnb + (size_t)b * T * DD;
  const unsigned short* rb = rnb + (size_t)b * T * DD;

  f32x4 acc[4][4];
#pragma unroll
  for (int i = 0; i < 4; ++i)
#pragma unroll
    for (int j = 0; j < 4; ++j) { f32x4 z = {0.f, 0.f, 0.f, 0.f}; acc[i][j] = z; }

  for (int kt = 0; kt < 16; ++kt) {
    bf16x8 a[4], bb[4];
#pragma unroll
    for (int fm = 0; fm < 4; ++fm)
      a[fm] = *(const bf16x8*)(pb + (size_t)(i0 + fm * 16 + (lane & 15)) * DD + kt * 32 + (lane >> 4) * 8);
#pragma unroll
    for (int fn = 0; fn < 4; ++fn)
      bb[fn] = *(const bf16x8*)(rb + (size_t)(j0 + fn * 16 + (lane & 15)) * DD + kt * 32 + (lane >> 4) * 8);
#pragma unroll
    for (int fm = 0; fm < 4; ++fm)
#pragma unroll
      for (int fn = 0; fn < 4; ++fn)
        acc[fm][fn] = __builtin_amdgcn_mfma_f32_16x16x32_bf16(a[fm], bb[fn], acc[fm][fn], 0, 0, 0);
  }

  const int* labB = labels + b * T;
  bool vj[4];
#pragma unroll
  for (int fn = 0; fn < 4; ++fn) vj[fn] = labB[j0 + fn * 16 + (lane & 15)] != IGNORE_INDEX;
  bool vi[4][4];
#pragma unroll
  for (int fm = 0; fm < 4; ++fm)
#pragma unroll
    for (int r4 = 0; r4 < 4; ++r4)
      vi[fm][r4] = labB[i0 + fm * 16 + ((lane >> 4) << 2) + r4] != IGNORE_INDEX;

  // precision: per row i, max over valid j
#pragma unroll
  for (int fm = 0; fm < 4; ++fm)
#pragma unroll
    for (int r4 = 0; r4 < 4; ++r4) {
      float v = NEG_INF;
#pragma unroll
      for (int fn = 0; fn < 4; ++fn)
        if (vj[fn]) v = fmaxf(v, acc[fm][fn][r4]);
      v = fmaxf(v, __shfl_xor(v, 1, 64));
      v = fmaxf(v, __shfl_xor(v, 2, 64));
      v = fmaxf(v, __shfl_xor(v, 4, 64));
      v = fmaxf(v, __shfl_xor(v, 8, 64));
      if ((lane & 15) == 0)
        atomicMax(&rowmax[b * T + i0 + fm * 16 + ((lane >> 4) << 2) + r4], fenc(v));
    }
  // recall: per col j, max over valid i
#pragma unroll
  for (int fn = 0; fn < 4; ++fn) {
    float v = NEG_INF;
#pragma unroll
    for (int fm = 0; fm < 4; ++fm)
#pragma unroll
      for (int r4 = 0; r4 < 4; ++r4)
        if (vi[fm][r4]) v = fmaxf(v, acc[fm][fn][r4]);
    v = fmaxf(v, __shfl_xor(v, 16, 64));
    v = fmaxf(v, __shfl_xor(v, 32, 64));
    if (lane < 16)
      atomicMax(&colmax[b * T + j0 + fn * 16 + lane], fenc(v));
  }
}

// ---------------- K5: per-batch F1 and mean loss ----------------
__global__ void k5_final(const int* __restrict__ labels, const unsigned* __restrict__ rowmax,
                         const unsigned* __restrict__ colmax, float* __restrict__ out) {
  const int t = threadIdx.x;  // 256
  const int lane = t & 63, wid = t >> 6;
  __shared__ float redC[4], redP[4], redR[4];
  __shared__ float totalS;
  if (t == 0) totalS = 0.f;
  __syncthreads();
  for (int b = 0; b < BB; ++b) {
    float c = 0.f, sp = 0.f, sr = 0.f;
    for (int d = t; d < T; d += 256) {
      if (labels[b * T + d] != IGNORE_INDEX) {
        c += 1.f;
        sp += fdec(rowmax[b * T + d]);
        sr += fdec(colmax[b * T + d]);
      }
    }
#pragma unroll
    for (int m = 1; m < 64; m <<= 1) {
      c += __shfl_xor(c, m, 64);
      sp += __shfl_xor(sp, m, 64);
      sr += __shfl_xor(sr, m, 64);
    }
    if (lane == 0) { redC[wid] = c; redP[wid] = sp; redR[wid] = sr; }
    __syncthreads();
    if (t == 0) {
      float cnt = redC[0] + redC[1] + redC[2] + redC[3];
      float dc = fmaxf(cnt, 1.f);
      float P = (redP[0] + redP[1] + redP[2] + redP[3]) / dc;
      float Rc = (redR[0] + redR[1] + redR[2] + redR[3]) / dc;
      float den = P + Rc;
      float f1 = (den > 0.f) ? (2.f * P * Rc / fmaxf(den, 1e-8f)) : 0.f;
      totalS += (cnt > 0.f) ? (1.f - f1) : 0.f;
    }
    __syncthreads();
  }
  if (t == 0) out[0] = totalS / (float)BB;
}

extern "C" void kernel_launch(void* const* d_in, const int* in_sizes, int n_in,
                              void* d_out, int out_size, void* d_ws, size_t ws_size,
                              hipStream_t stream) {
  const float* logits = (const float*)d_in[0];
  const int* labels = (const int*)d_in[1];
  const float* E = (const float*)d_in[2];
  float* out = (float*)d_out;
  char* ws = (char*)d_ws;

  // ws layout (bytes):
  unsigned short* eT = (unsigned short*)(ws);                 // 512*32128*2 = 32,899,072
  float* soft        = (float*)(ws + 32899072);               // 4096*512*4  =  8,388,608
  unsigned short* pnb = (unsigned short*)(ws + 41287680);     // 4096*512*2  =  4,194,304
  unsigned short* rnb = (unsigned short*)(ws + 45481984);     // 4096*512*2  =  4,194,304
  unsigned* rowmax   = (unsigned*)(ws + 49676288);            // 4096*4
  unsigned* colmax   = (unsigned*)(ws + 49692672);            // 4096*4  -> total 49,709,056 B

  // 100 KB dynamic LDS for the main GEMM
  hipFuncSetAttribute((const void*)k2_gemm, hipFuncAttributeMaxDynamicSharedMemorySize, 102400);

  k0_init<<<8192, 256, 0, stream>>>(soft, rowmax, colmax);
  k1_transpose<<<dim3(V / 64, DD / 64), 256, 0, stream>>>(E, eT);
  k2_gemm<<<dim3(R / 128, NCHUNK), 512, 102400, stream>>>(logits, eT, soft);
  k3_norm<<<R, 256, 0, stream>>>(soft, labels, E, pnb, rnb);
  k4_sim<<<dim3(8, 8, 8), 64, 0, stream>>>(pnb, rnb, labels, rowmax, colmax);
  k5_final<<<1, 256, 0, stream>>>(labels, rowmax, colmax, out);
}

// Round 2
// 872.281 us; speedup vs baseline: 1.0928x; 1.0928x over previous
//
#include <hip/hip_runtime.h>
#include <hip/hip_bf16.h>

// SoftBERTScore loss, MI355X/gfx950.
// K0 init -> K1 E -> tiled/swizzled bf16 eT -> K2 exp(logits)@E (MFMA, gload_lds B,
// swizzled LDS, split-K atomic) -> K3 normalize+gather -> K4 sim MFMA + masked max -> K5 loss.

#define IGNORE_INDEX (-100)
#define NEG_INF (-1e9f)

typedef float f32x4 __attribute__((ext_vector_type(4)));
typedef __bf16 bf16x8 __attribute__((ext_vector_type(8)));

static constexpr int BB = 8, T = 512, V = 32128, DD = 512;
static constexpr int R = BB * T;              // 4096 rows
static constexpr int KITERS = V / 32;         // 1004 k-tiles
static constexpr int NCHUNK = 8;              // split-K
static constexpr int CHUNK = (KITERS + NCHUNK - 1) / NCHUNK;  // 126

__device__ __forceinline__ unsigned short f2bf(float f) {
  unsigned u = __float_as_uint(f);
  u += 0x7fffu + ((u >> 16) & 1u);   // RNE
  return (unsigned short)(u >> 16);
}
__device__ __forceinline__ unsigned pack2(float lo, float hi) {
  return (unsigned)f2bf(lo) | ((unsigned)f2bf(hi) << 16);
}
__device__ __forceinline__ unsigned fenc(float f) {
  unsigned u = __float_as_uint(f);
  return (u & 0x80000000u) ? ~u : (u | 0x80000000u);
}
__device__ __forceinline__ float fdec(unsigned e) {
  unsigned u = (e & 0x80000000u) ? (e & 0x7fffffffu) : ~e;
  return __uint_as_float(u);
}
__device__ __forceinline__ void gload16(const void* g, void* l) {
  __builtin_amdgcn_global_load_lds(
      (const __attribute__((address_space(1))) unsigned*)g,
      (__attribute__((address_space(3))) unsigned*)l, 16, 0, 0);
}

// ---------------- K0: zero soft accumulator, init max buffers ----------------
__global__ void k0_init(float* __restrict__ soft, unsigned* __restrict__ rowmax,
                        unsigned* __restrict__ colmax) {
  int idx = blockIdx.x * 256 + threadIdx.x;
  if (idx < R * DD) soft[idx] = 0.0f;
  if (idx < R) { rowmax[idx] = fenc(NEG_INF); colmax[idx] = fenc(NEG_INF); }
}

// ---------------- K1: E [V][D] fp32 -> eT tiled bf16 ----------------
// eT layout: tile it (v in [32it,32it+32)) is contiguous 32KB:
//   element (col=d, k8, j) at it*16384 + col*32 + (k8 ^ ((col>>1)&3))*8 + j   (ushort units)
__global__ void k1_pack(const float* __restrict__ E, unsigned short* __restrict__ eT) {
  __shared__ unsigned short sm[32][520];   // +8 pad: spreads rows across banks
  const int it = blockIdx.x;
  const int v0 = it * 32;
  const int t = threadIdx.x;               // 256
  {
    const int row = t >> 3, colq = t & 7;
    const float* src = E + (size_t)(v0 + row) * DD + colq * 4;
#pragma unroll
    for (int u = 0; u < 16; ++u) {
      float4 x = *(const float4*)(src + u * 32);
      uint2 w;
      w.x = pack2(x.x, x.y);
      w.y = pack2(x.z, x.w);
      *(uint2*)&sm[row][colq * 4 + u * 32] = w;
    }
  }
  __syncthreads();
  {
    const int c0 = 2 * t;                  // cols c0, c0+1
    unsigned short va[32], vb[32];
#pragma unroll
    for (int v = 0; v < 32; ++v) {
      unsigned w = *(const unsigned*)&sm[v][c0];
      va[v] = (unsigned short)w;
      vb[v] = (unsigned short)(w >> 16);
    }
    unsigned short* base = eT + (size_t)it * 16384;
#pragma unroll
    for (int cc = 0; cc < 2; ++cc) {
      const int col = c0 + cc;
      unsigned short* ob = base + col * 32;
#pragma unroll
      for (int k8 = 0; k8 < 4; ++k8) {
        const unsigned short* vv = cc ? (vb + k8 * 8) : (va + k8 * 8);
        uint4 w;
        w.x = (unsigned)vv[0] | ((unsigned)vv[1] << 16);
        w.y = (unsigned)vv[2] | ((unsigned)vv[3] << 16);
        w.z = (unsigned)vv[4] | ((unsigned)vv[5] << 16);
        w.w = (unsigned)vv[6] | ((unsigned)vv[7] << 16);
        int k8p = k8 ^ ((col >> 1) & 3);
        *(uint4*)(ob + k8p * 8) = w;
      }
    }
  }
}

// ---------------- K2: soft_unnorm = exp(logits) @ E  (bf16 MFMA) ----------------
// BM=128 x BN=512, BK=32, 512 threads (8 waves 2x4, wave tile 64x128).
// B staged via global_load_lds (tile-contiguous eT); A staged fp32->exp->bf16 with
// swizzled ds_write. LDS 80KB dynamic: A[2][128][32]ush @0, B[2][512][32]ush @8192ush.
__launch_bounds__(512, 2)
__global__ void k2_gemm(const float* __restrict__ logits,
                        const unsigned short* __restrict__ eT,
                        float* __restrict__ soft) {
  extern __shared__ unsigned short smem[];
  unsigned short* Asm = smem;              // 2 x 4096 ush
  unsigned short* Bsm = smem + 8192;       // 2 x 16384 ush
  const int t = threadIdx.x;
  const int lane = t & 63, wid = t >> 6;
  const int wm = wid >> 2, wn = wid & 3;
  const int rowbase = blockIdx.x * 128;
  const int it0 = blockIdx.y * CHUNK;
  const int itEnd = (it0 + CHUNK < KITERS) ? (it0 + CHUNK) : KITERS;

  const int am = t >> 2, akq = t & 3;
  const int aswz = akq ^ ((am >> 1) & 3);
  const float* aG = logits + (size_t)(rowbase + am) * V + akq * 8;
  const unsigned short* bG = eT + t * 8;

  f32x4 acc[4][8];
#pragma unroll
  for (int i = 0; i < 4; ++i)
#pragma unroll
    for (int j = 0; j < 8; ++j) { f32x4 z = {0.f, 0.f, 0.f, 0.f}; acc[i][j] = z; }

  // prologue: stage it0 into buffer 0
  {
#pragma unroll
    for (int i = 0; i < 4; ++i)
      gload16(bG + (size_t)it0 * 16384 + i * 4096, Bsm + t * 8 + i * 4096);
    float4 a0 = *(const float4*)(aG + (size_t)it0 * 32);
    float4 a1 = *(const float4*)(aG + (size_t)it0 * 32 + 4);
    uint4 w;
    w.x = pack2(__expf(a0.x), __expf(a0.y));
    w.y = pack2(__expf(a0.z), __expf(a0.w));
    w.z = pack2(__expf(a1.x), __expf(a1.y));
    w.w = pack2(__expf(a1.z), __expf(a1.w));
    *(uint4*)(Asm + am * 32 + aswz * 8) = w;
  }
  __syncthreads();

  int cur = 0;
  for (int it = it0; it < itEnd; ++it) {
    const int nb = cur ^ 1;
    const bool hasNext = (it + 1) < itEnd;
    float4 a0, a1;
    if (hasNext) {
#pragma unroll
      for (int i = 0; i < 4; ++i)
        gload16(bG + (size_t)(it + 1) * 16384 + i * 4096,
                Bsm + nb * 16384 + t * 8 + i * 4096);
      a0 = *(const float4*)(aG + (size_t)(it + 1) * 32);
      a1 = *(const float4*)(aG + (size_t)(it + 1) * 32 + 4);
    }
    const unsigned short* As = Asm + cur * 4096;
    const unsigned short* Bs = Bsm + cur * 16384;
    bf16x8 af[4], bfr[8];
#pragma unroll
    for (int fm = 0; fm < 4; ++fm) {
      int row = wm * 64 + fm * 16 + (lane & 15);
      af[fm] = *(const bf16x8*)(As + row * 32 + (((lane >> 4) ^ ((row >> 1) & 3)) << 3));
    }
#pragma unroll
    for (int fn = 0; fn < 8; ++fn) {
      int col = wn * 128 + fn * 16 + (lane & 15);
      bfr[fn] = *(const bf16x8*)(Bs + col * 32 + (((lane >> 4) ^ ((col >> 1) & 3)) << 3));
    }
#pragma unroll
    for (int fm = 0; fm < 4; ++fm)
#pragma unroll
      for (int fn = 0; fn < 8; ++fn)
        acc[fm][fn] = __builtin_amdgcn_mfma_f32_16x16x32_bf16(af[fm], bfr[fn], acc[fm][fn], 0, 0, 0);
    if (hasNext) {
      uint4 w;
      w.x = pack2(__expf(a0.x), __expf(a0.y));
      w.y = pack2(__expf(a0.z), __expf(a0.w));
      w.z = pack2(__expf(a1.x), __expf(a1.y));
      w.w = pack2(__expf(a1.z), __expf(a1.w));
      *(uint4*)(Asm + nb * 4096 + am * 32 + aswz * 8) = w;
    }
    __syncthreads();
    cur ^= 1;
  }

  // epilogue: split-K atomic accumulate
#pragma unroll
  for (int fm = 0; fm < 4; ++fm)
#pragma unroll
    for (int fn = 0; fn < 8; ++fn)
#pragma unroll
      for (int r4 = 0; r4 < 4; ++r4) {
        int row = rowbase + wm * 64 + fm * 16 + ((lane >> 4) << 2) + r4;
        int col = wn * 128 + fn * 16 + (lane & 15);
        atomicAdd(&soft[(size_t)row * DD + col], acc[fm][fn][r4]);
      }
}

// ---------------- K3: normalize soft_pred & gathered hard_ref -> bf16 ----------------
__global__ void k3_norm(const float* __restrict__ soft, const int* __restrict__ labels,
                        const float* __restrict__ E,
                        unsigned short* __restrict__ pnb, unsigned short* __restrict__ rnb) {
  const int r = blockIdx.x;
  const int t = threadIdx.x;            // 256
  const int lane = t & 63, wid = t >> 6;
  __shared__ float red[8];

  const float* row = soft + (size_t)r * DD;
  float v0 = row[t], v1 = row[t + 256];
  float ss = v0 * v0 + v1 * v1;
#pragma unroll
  for (int m = 1; m < 64; m <<= 1) ss += __shfl_xor(ss, m, 64);
  if (lane == 0) red[wid] = ss;
  __syncthreads();
  float s = red[0] + red[1] + red[2] + red[3];
  float sc = 1.0f / fmaxf(sqrtf(s), 1e-12f);
  pnb[(size_t)r * DD + t] = f2bf(v0 * sc);
  pnb[(size_t)r * DD + t + 256] = f2bf(v1 * sc);

  int lab = labels[r];
  int safe = (lab == IGNORE_INDEX) ? 0 : lab;
  const float* hrow = E + (size_t)safe * DD;
  float h0 = hrow[t], h1 = hrow[t + 256];
  float ss2 = h0 * h0 + h1 * h1;
#pragma unroll
  for (int m = 1; m < 64; m <<= 1) ss2 += __shfl_xor(ss2, m, 64);
  if (lane == 0) red[4 + wid] = ss2;
  __syncthreads();
  float s2 = red[4] + red[5] + red[6] + red[7];
  float sc2 = 1.0f / fmaxf(sqrtf(s2), 1e-12f);
  rnb[(size_t)r * DD + t] = f2bf(h0 * sc2);
  rnb[(size_t)r * DD + t + 256] = f2bf(h1 * sc2);
}

// ---------------- K4: sim = p_n @ r_n^T per batch; masked row/col maxes ----------------
__global__ void k4_sim(const unsigned short* __restrict__ pnb,
                       const unsigned short* __restrict__ rnb,
                       const int* __restrict__ labels,
                       unsigned* __restrict__ rowmax, unsigned* __restrict__ colmax) {
  const int lane = threadIdx.x;  // 64
  const int jt = blockIdx.x, it = blockIdx.y, b = blockIdx.z;
  const int i0 = it * 64, j0 = jt * 64;
  const unsigned short* pb = pnb + (size_t)b * T * DD;
  const unsigned short* rb = rnb + (size_t)b * T * DD;

  f32x4 acc[4][4];
#pragma unroll
  for (int i = 0; i < 4; ++i)
#pragma unroll
    for (int j = 0; j < 4; ++j) { f32x4 z = {0.f, 0.f, 0.f, 0.f}; acc[i][j] = z; }

  for (int kt = 0; kt < 16; ++kt) {
    bf16x8 a[4], bb[4];
#pragma unroll
    for (int fm = 0; fm < 4; ++fm)
      a[fm] = *(const bf16x8*)(pb + (size_t)(i0 + fm * 16 + (lane & 15)) * DD + kt * 32 + (lane >> 4) * 8);
#pragma unroll
    for (int fn = 0; fn < 4; ++fn)
      bb[fn] = *(const bf16x8*)(rb + (size_t)(j0 + fn * 16 + (lane & 15)) * DD + kt * 32 + (lane >> 4) * 8);
#pragma unroll
    for (int fm = 0; fm < 4; ++fm)
#pragma unroll
      for (int fn = 0; fn < 4; ++fn)
        acc[fm][fn] = __builtin_amdgcn_mfma_f32_16x16x32_bf16(a[fm], bb[fn], acc[fm][fn], 0, 0, 0);
  }

  const int* labB = labels + b * T;
  bool vj[4];
#pragma unroll
  for (int fn = 0; fn < 4; ++fn) vj[fn] = labB[j0 + fn * 16 + (lane & 15)] != IGNORE_INDEX;
  bool vi[4][4];
#pragma unroll
  for (int fm = 0; fm < 4; ++fm)
#pragma unroll
    for (int r4 = 0; r4 < 4; ++r4)
      vi[fm][r4] = labB[i0 + fm * 16 + ((lane >> 4) << 2) + r4] != IGNORE_INDEX;

#pragma unroll
  for (int fm = 0; fm < 4; ++fm)
#pragma unroll
    for (int r4 = 0; r4 < 4; ++r4) {
      float v = NEG_INF;
#pragma unroll
      for (int fn = 0; fn < 4; ++fn)
        if (vj[fn]) v = fmaxf(v, acc[fm][fn][r4]);
      v = fmaxf(v, __shfl_xor(v, 1, 64));
      v = fmaxf(v, __shfl_xor(v, 2, 64));
      v = fmaxf(v, __shfl_xor(v, 4, 64));
      v = fmaxf(v, __shfl_xor(v, 8, 64));
      if ((lane & 15) == 0)
        atomicMax(&rowmax[b * T + i0 + fm * 16 + ((lane >> 4) << 2) + r4], fenc(v));
    }
#pragma unroll
  for (int fn = 0; fn < 4; ++fn) {
    float v = NEG_INF;
#pragma unroll
    for (int fm = 0; fm < 4; ++fm)
#pragma unroll
      for (int r4 = 0; r4 < 4; ++r4)
        if (vi[fm][r4]) v = fmaxf(v, acc[fm][fn][r4]);
    v = fmaxf(v, __shfl_xor(v, 16, 64));
    v = fmaxf(v, __shfl_xor(v, 32, 64));
    if (lane < 16)
      atomicMax(&colmax[b * T + j0 + fn * 16 + lane], fenc(v));
  }
}

// ---------------- K5: per-batch F1 and mean loss ----------------
__global__ void k5_final(const int* __restrict__ labels, const unsigned* __restrict__ rowmax,
                         const unsigned* __restrict__ colmax, float* __restrict__ out) {
  const int t = threadIdx.x;  // 256
  const int lane = t & 63, wid = t >> 6;
  __shared__ float redC[4], redP[4], redR[4];
  __shared__ float totalS;
  if (t == 0) totalS = 0.f;
  __syncthreads();
  for (int b = 0; b < BB; ++b) {
    float c = 0.f, sp = 0.f, sr = 0.f;
    for (int d = t; d < T; d += 256) {
      if (labels[b * T + d] != IGNORE_INDEX) {
        c += 1.f;
        sp += fdec(rowmax[b * T + d]);
        sr += fdec(colmax[b * T + d]);
      }
    }
#pragma unroll
    for (int m = 1; m < 64; m <<= 1) {
      c += __shfl_xor(c, m, 64);
      sp += __shfl_xor(sp, m, 64);
      sr += __shfl_xor(sr, m, 64);
    }
    if (lane == 0) { redC[wid] = c; redP[wid] = sp; redR[wid] = sr; }
    __syncthreads();
    if (t == 0) {
      float cnt = redC[0] + redC[1] + redC[2] + redC[3];
      float dc = fmaxf(cnt, 1.f);
      float P = (redP[0] + redP[1] + redP[2] + redP[3]) / dc;
      float Rc = (redR[0] + redR[1] + redR[2] + redR[3]) / dc;
      float den = P + Rc;
      float f1 = (den > 0.f) ? (2.f * P * Rc / fmaxf(den, 1e-8f)) : 0.f;
      totalS += (cnt > 0.f) ? (1.f - f1) : 0.f;
    }
    __syncthreads();
  }
  if (t == 0) out[0] = totalS / (float)BB;
}

extern "C" void kernel_launch(void* const* d_in, const int* in_sizes, int n_in,
                              void* d_out, int out_size, void* d_ws, size_t ws_size,
                              hipStream_t stream) {
  const float* logits = (const float*)d_in[0];
  const int* labels = (const int*)d_in[1];
  const float* E = (const float*)d_in[2];
  float* out = (float*)d_out;
  char* ws = (char*)d_ws;

  unsigned short* eT = (unsigned short*)(ws);                 // 1004*16384*2 = 32,899,072
  float* soft        = (float*)(ws + 32899072);               // 4096*512*4  =  8,388,608
  unsigned short* pnb = (unsigned short*)(ws + 41287680);     // 4096*512*2  =  4,194,304
  unsigned short* rnb = (unsigned short*)(ws + 45481984);     // 4096*512*2  =  4,194,304
  unsigned* rowmax   = (unsigned*)(ws + 49676288);            // 4096*4
  unsigned* colmax   = (unsigned*)(ws + 49692672);            // 4096*4

  hipFuncSetAttribute((const void*)k2_gemm, hipFuncAttributeMaxDynamicSharedMemorySize, 81920);

  k0_init<<<8192, 256, 0, stream>>>(soft, rowmax, colmax);
  k1_pack<<<KITERS, 256, 0, stream>>>(E, eT);
  k2_gemm<<<dim3(R / 128, NCHUNK), 512, 81920, stream>>>(logits, eT, soft);
  k3_norm<<<R, 256, 0, stream>>>(soft, labels, E, pnb, rnb);
  k4_sim<<<dim3(8, 8, 8), 64, 0, stream>>>(pnb, rnb, labels, rowmax, colmax);
  k5_final<<<1, 256, 0, stream>>>(labels, rowmax, colmax, out);
}